// Round 9
// baseline (11314.001 us; speedup 1.0000x reference)
//
#include <hip/hip_runtime.h>
#include <math.h>

// Problem dims
#define BATCH 32
#define SEQ   500
#define NQ    3000
#define EMB   256
#define HID   256
#define ROWS  (BATCH * SEQ)        // 16000
#define X_K   (2 * NQ)             // 6000

typedef short short8 __attribute__((ext_vector_type(8)));
typedef float f32x4  __attribute__((ext_vector_type(4)));

// ---------------- bf16 split helpers ----------------
__device__ __forceinline__ unsigned bf16_rne(float f) {
    unsigned u = __float_as_uint(f);
    return (u + 0x7fffu + ((u >> 16) & 1u)) >> 16;
}
__device__ __forceinline__ unsigned pack_bf16_rn(float a, float b) {
    return bf16_rne(a) | (bf16_rne(b) << 16);   // low16 = a, high16 = b
}

// LDS tile layout (per 128-row x 32-k tile, 16 KB): see prior rounds.
__device__ __forceinline__ void stage_tile(unsigned char* lbase, int row, int cg, float4 v) {
    unsigned ux = __float_as_uint(v.x), uy = __float_as_uint(v.y);
    unsigned uz = __float_as_uint(v.z), uw = __float_as_uint(v.w);
    unsigned hx = ux & 0xffff0000u, hy = uy & 0xffff0000u;
    unsigned hz = uz & 0xffff0000u, hw = uw & 0xffff0000u;
    unsigned hi01 = (hx >> 16) | hy;
    unsigned hi23 = (hz >> 16) | hw;
    unsigned lo01 = pack_bf16_rn(v.x - __uint_as_float(hx), v.y - __uint_as_float(hy));
    unsigned lo23 = pack_bf16_rn(v.z - __uint_as_float(hz), v.w - __uint_as_float(hw));
    const int slot = cg ^ (row & 7);
    const int pf   = (row >> 3) & 1;
    uint4 w = pf ? make_uint4(lo01, lo23, hi01, hi23)
                 : make_uint4(hi01, hi23, lo01, lo23);
    *reinterpret_cast<uint4*>(lbase + row * 128 + (slot << 4)) = w;
}

__device__ __forceinline__ void read_frag(const unsigned char* lbase, int row, int c,
                                          short8& hi, short8& lo) {
    const int r7 = row & 7;
    const int pf = (row >> 3) & 1;
    const unsigned char* rbase = lbase + row * 128;
    const int s0 = (((c << 1) | 0) ^ r7) << 4;
    const int s1 = (((c << 1) | 1) ^ r7) << 4;
    const int oh = pf << 3;
    const int ol = (pf ^ 1) << 3;
    uint2 h0 = *reinterpret_cast<const uint2*>(rbase + s0 + oh);
    uint2 h1 = *reinterpret_cast<const uint2*>(rbase + s1 + oh);
    uint2 l0 = *reinterpret_cast<const uint2*>(rbase + s0 + ol);
    uint2 l1 = *reinterpret_cast<const uint2*>(rbase + s1 + ol);
    hi = __builtin_bit_cast(short8, make_uint4(h0.x, h0.y, h1.x, h1.y));
    lo = __builtin_bit_cast(short8, make_uint4(l0.x, l0.y, l1.x, l1.y));
}

// ---------------- split-bf16 MFMA GEMM (unchanged, verified round 5) ----------------
template<bool HASBIAS>
__global__ __launch_bounds__(256, 2)
void gemm_mfma(const float* __restrict__ A, const float* __restrict__ B,
               const float* __restrict__ bias, float* __restrict__ C,
               int M, int N, int K, int ldc,
               long long sA, long long sB, long long sC)
{
    A += (long long)blockIdx.z * sA;
    B += (long long)blockIdx.z * sB;
    C += (long long)blockIdx.z * sC;

    __shared__ __align__(16) unsigned char lds[32768];
    unsigned char* Al_ = lds;
    unsigned char* Bl_ = lds + 16384;

    const int tid = threadIdx.x;
    const int m0 = blockIdx.y * 128;
    const int n0 = blockIdx.x * 128;

    const int srow = tid >> 3;
    const int scg  = tid & 7;

    const int wid = tid >> 6;
    const int wm  = wid >> 1;
    const int wn  = wid & 1;
    const int lane = tid & 63;
    const int fr  = lane & 15;
    const int fc  = lane >> 4;

    f32x4 acc[4][4];
    #pragma unroll
    for (int i = 0; i < 4; ++i)
        #pragma unroll
        for (int j = 0; j < 4; ++j)
            acc[i][j] = (f32x4){0.f, 0.f, 0.f, 0.f};

    const int ktiles = (K + 31) >> 5;
    for (int kt = 0; kt < ktiles; ++kt) {
        const int gk = (kt << 5) + scg * 4;
        #pragma unroll
        for (int rd = 0; rd < 4; ++rd) {
            const int row = rd * 32 + srow;
            {
                const int gm = m0 + row;
                float4 v = make_float4(0.f, 0.f, 0.f, 0.f);
                if (gm < M && gk < K)
                    v = *reinterpret_cast<const float4*>(A + (long long)gm * K + gk);
                stage_tile(Al_, row, scg, v);
            }
            {
                const int gn = n0 + row;
                float4 v = make_float4(0.f, 0.f, 0.f, 0.f);
                if (gn < N && gk < K)
                    v = *reinterpret_cast<const float4*>(B + (long long)gn * K + gk);
                stage_tile(Bl_, row, scg, v);
            }
        }
        __syncthreads();

        short8 ah[4], al[4], bh[4], bl[4];
        #pragma unroll
        for (int mi = 0; mi < 4; ++mi)
            read_frag(Al_, wm * 64 + mi * 16 + fr, fc, ah[mi], al[mi]);
        #pragma unroll
        for (int ni = 0; ni < 4; ++ni)
            read_frag(Bl_, wn * 64 + ni * 16 + fr, fc, bh[ni], bl[ni]);

        #pragma unroll
        for (int mi = 0; mi < 4; ++mi) {
            #pragma unroll
            for (int ni = 0; ni < 4; ++ni) {
                acc[mi][ni] = __builtin_amdgcn_mfma_f32_16x16x32_bf16(al[mi], bh[ni], acc[mi][ni], 0, 0, 0);
                acc[mi][ni] = __builtin_amdgcn_mfma_f32_16x16x32_bf16(ah[mi], bl[ni], acc[mi][ni], 0, 0, 0);
                acc[mi][ni] = __builtin_amdgcn_mfma_f32_16x16x32_bf16(ah[mi], bh[ni], acc[mi][ni], 0, 0, 0);
            }
        }
        __syncthreads();
    }

    #pragma unroll
    for (int ni = 0; ni < 4; ++ni) {
        const int col = n0 + wn * 64 + ni * 16 + fr;
        if (col >= N) continue;
        const float bv = HASBIAS ? bias[col] : 0.f;
        #pragma unroll
        for (int mi = 0; mi < 4; ++mi) {
            #pragma unroll
            for (int q = 0; q < 4; ++q) {
                const int rw = m0 + wm * 64 + mi * 16 + fc * 4 + q;
                if (rw < M) C[(long long)rw * ldc + col] = acc[mi][ni][q] + bv;
            }
        }
    }
}

// ---------------- generic transpose: in[R,C] -> out[C,R], batched ----------------
__global__ __launch_bounds__(256)
void trans_kernel(const float* __restrict__ in, float* __restrict__ out,
                  int R, int C, long long sIn, long long sOut)
{
    in  += (long long)blockIdx.z * sIn;
    out += (long long)blockIdx.z * sOut;
    __shared__ float t[32][33];
    const int r0 = blockIdx.y * 32, c0 = blockIdx.x * 32;
    const int tx = threadIdx.x & 31, ty = threadIdx.x >> 5;
    #pragma unroll
    for (int i = 0; i < 32; i += 8) {
        const int r = r0 + ty + i, c = c0 + tx;
        t[ty + i][tx] = (r < R && c < C) ? in[(long long)r * C + c] : 0.f;
    }
    __syncthreads();
    #pragma unroll
    for (int i = 0; i < 32; i += 8) {
        const int r = r0 + tx, c = c0 + ty + i;
        if (c < C && r < R) out[(long long)c * R + r] = t[tx][ty + i];
    }
}

// ---------------- GRU init: zero h state + flags (runs every launch/replay) ------
__global__ __launch_bounds__(256)
void gru_init_kernel(float* __restrict__ h_g, unsigned* __restrict__ pflag,
                     unsigned* __restrict__ hflag)
{
    const int i = blockIdx.x * 256 + threadIdx.x;
    if (i < 64 * HID) h_g[i] = 0.f;
    if (i < 64) { pflag[i] = 0u; hflag[i] = 0u; }
}

// ---------------- GRU: weights-in-registers, 4-way K-split, flag-synced ----------
// 256 blocks = (2 gru x 32 batch x 4 k-quarter). Each block holds its W_hh slice
// (64 k-rows x 768 gate-cols = 192 floats/thread, compile-time-indexed) in VGPRs
// -> ZERO weight re-streaming per step (was 786 KB/step/CU = the r5/r7 bottleneck).
// Per step: kq=1..3 produce 64-k partial preacts -> global (agent atomics) -> pflag;
// kq=0 computes own partials, combines, gates, publishes h -> hflag.
// Flow control: producers wait hf>=t+1 before writing step t+1 partials, so the
// consumer has always consumed step-t partials first (no overwrite race).
// Co-residency: ~230 VGPRs -> >=1 block/CU capacity (2 waves/SIMD fit), so
// capacity (>=256) >= grid (256): all blocks resident regardless of dispatch order.
__global__ __launch_bounds__(256, 1)
void gru_kernel(const float* __restrict__ xp1, const float* __restrict__ xp2,
                const float* __restrict__ wT1, const float* __restrict__ wT2,
                const float* __restrict__ bh1, const float* __restrict__ bh2,
                float* __restrict__ out1, float* __restrict__ out2,
                float* __restrict__ partials, float* __restrict__ h_g,
                unsigned* __restrict__ pflag, unsigned* __restrict__ hflag)
{
    __shared__ float h_lds[HID];         // consumer: full h; producers: 64-slice

    const int bid = blockIdx.x;
    const int grp = bid >> 2;            // 0..63 = (g,b)
    const int kq  = bid & 3;             // k-quarter
    const int g   = grp >> 5;
    const int b   = grp & 31;
    const int tid = threadIdx.x;
    const int j   = tid;                 // unit/gate column 0..255

    const float* wT = g ? wT2 : wT1;
    float* part     = partials + ((long long)grp * 4 + kq) * 768;
    float* hg       = h_g + grp * HID;
    unsigned* pf    = pflag + grp;
    unsigned* hf    = hflag + grp;

    // ---- load W slice into registers: wreg[kl][c] = wT[(64*kq+kl)*768 + c*256 + j]
    float wreg[64][3];
    {
        const float* wb = wT + (long long)(64 * kq) * 768 + j;
        #pragma unroll
        for (int kl = 0; kl < 64; ++kl) {
            wreg[kl][0] = wb[kl * 768];
            wreg[kl][1] = wb[kl * 768 + 256];
            wreg[kl][2] = wb[kl * 768 + 512];
        }
    }

    if (kq == 0) {
        // ================= consumer/combiner =================
        const float* xp = (g ? xp2 : xp1) + (long long)b * SEQ * 768;
        const float* bh = g ? bh2 : bh1;
        float* out      = (g ? out2 : out1) + (long long)b * SEQ * HID;
        const float br = bh[j], bz = bh[HID + j], bn = bh[2 * HID + j];

        h_lds[j] = 0.f;
        __syncthreads();

        for (int t = 0; t < SEQ; ++t) {
            // prefetch x-projection row (latency hidden under fma chain)
            const float* xrow = xp + (long long)t * 768;
            const float xr = xrow[j], xz = xrow[HID + j], xn = xrow[2 * HID + j];

            // own partials over k = 0..63 (h_lds broadcast reads)
            float ar = 0.f, az = 0.f, an = 0.f;
            #pragma unroll
            for (int kl = 0; kl < 64; ++kl) {
                const float hk = h_lds[kl];
                ar = fmaf(wreg[kl][0], hk, ar);
                az = fmaf(wreg[kl][1], hk, az);
                an = fmaf(wreg[kl][2], hk, an);
            }

            // wait for 3 producers' step-t partials
            if (tid == 0) {
                const unsigned target = 3u * (unsigned)(t + 1);
                while (__hip_atomic_load(pf, __ATOMIC_ACQUIRE, __HIP_MEMORY_SCOPE_AGENT) < target)
                    __builtin_amdgcn_s_sleep(2);
            }
            __syncthreads();

            // combine partials (agent-scope loads: coherent, skip stale L1)
            float gr = ar + br, gz = az + bz, gn = an + bn;
            #pragma unroll
            for (int q2 = 1; q2 < 4; ++q2) {
                const float* pp = partials + ((long long)grp * 4 + q2) * 768;
                gr += __hip_atomic_load(&pp[j],           __ATOMIC_RELAXED, __HIP_MEMORY_SCOPE_AGENT);
                gz += __hip_atomic_load(&pp[HID + j],     __ATOMIC_RELAXED, __HIP_MEMORY_SCOPE_AGENT);
                gn += __hip_atomic_load(&pp[2 * HID + j], __ATOMIC_RELAXED, __HIP_MEMORY_SCOPE_AGENT);
            }
            const float r = 1.f / (1.f + __expf(-(xr + gr)));
            const float z = 1.f / (1.f + __expf(-(xz + gz)));
            const float n = tanhf(xn + r * gn);
            const float hnew = (1.f - z) * n + z * h_lds[j];
            out[(long long)t * HID + j] = hnew;
            __hip_atomic_store(&hg[j], hnew, __ATOMIC_RELAXED, __HIP_MEMORY_SCOPE_AGENT);
            h_lds[j] = hnew;
            __syncthreads();             // drains all threads' stores + h_lds visible
            if (tid == 0)
                __hip_atomic_fetch_add(hf, 1u, __ATOMIC_RELEASE, __HIP_MEMORY_SCOPE_AGENT);
        }
    } else {
        // ================= producer =================
        for (int t = 0; t < SEQ; ++t) {
            // wait for h after step t-1 (t=0: init zeros, passes immediately)
            if (tid == 0) {
                while (__hip_atomic_load(hf, __ATOMIC_ACQUIRE, __HIP_MEMORY_SCOPE_AGENT) < (unsigned)t)
                    __builtin_amdgcn_s_sleep(2);
            }
            __syncthreads();
            if (tid < 64)
                h_lds[tid] = __hip_atomic_load(&hg[64 * kq + tid],
                                               __ATOMIC_RELAXED, __HIP_MEMORY_SCOPE_AGENT);
            __syncthreads();

            float ar = 0.f, az = 0.f, an = 0.f;
            #pragma unroll
            for (int kl = 0; kl < 64; ++kl) {
                const float hk = h_lds[kl];
                ar = fmaf(wreg[kl][0], hk, ar);
                az = fmaf(wreg[kl][1], hk, az);
                an = fmaf(wreg[kl][2], hk, an);
            }
            __hip_atomic_store(&part[j],           ar, __ATOMIC_RELAXED, __HIP_MEMORY_SCOPE_AGENT);
            __hip_atomic_store(&part[HID + j],     az, __ATOMIC_RELAXED, __HIP_MEMORY_SCOPE_AGENT);
            __hip_atomic_store(&part[2 * HID + j], an, __ATOMIC_RELAXED, __HIP_MEMORY_SCOPE_AGENT);
            __syncthreads();             // drains all threads' partial stores
            if (tid == 0)
                __hip_atomic_fetch_add(pf, 1u, __ATOMIC_RELEASE, __HIP_MEMORY_SCOPE_AGENT);
        }
    }
}

// ---------------- softmax over rows of length 500 (in place) ----------------
__global__ __launch_bounds__(256)
void softmax_kernel(float* __restrict__ s)
{
    float* p = s + (long long)blockIdx.x * SEQ;
    const int tid = threadIdx.x;
    __shared__ float red[256];

    const float v0 = (tid < SEQ) ? p[tid] : -1e30f;
    const float v1 = (tid + 256 < SEQ) ? p[tid + 256] : -1e30f;
    red[tid] = fmaxf(v0, v1);
    __syncthreads();
    for (int o = 128; o > 0; o >>= 1) {
        if (tid < o) red[tid] = fmaxf(red[tid], red[tid + o]);
        __syncthreads();
    }
    const float m = red[0];
    __syncthreads();
    const float e0 = (tid < SEQ) ? __expf(v0 - m) : 0.f;
    const float e1 = (tid + 256 < SEQ) ? __expf(v1 - m) : 0.f;
    red[tid] = e0 + e1;
    __syncthreads();
    for (int o = 128; o > 0; o >>= 1) {
        if (tid < o) red[tid] += red[tid + o];
        __syncthreads();
    }
    const float inv = 1.f / red[0];
    if (tid < SEQ) p[tid] = e0 * inv;
    if (tid + 256 < SEQ) p[tid + 256] = e1 * inv;
}

// ---------------- column sum: [32][500][256] -> [32][256] ----------------
__global__ __launch_bounds__(256)
void colsum_kernel(const float* __restrict__ x, float* __restrict__ out)
{
    const int b = blockIdx.x, hh = threadIdx.x;
    const float* p = x + (long long)b * SEQ * HID + hh;
    float s = 0.f;
    for (int t = 0; t < SEQ; ++t) s += p[t * HID];
    out[b * HID + hh] = s;
}

// ---------------- fused_h combine: ens[...,256+h] = colsum - tmp ----------------
__global__ __launch_bounds__(256)
void combine_kernel(const float* __restrict__ tmp, const float* __restrict__ cs,
                    float* __restrict__ ens)
{
    const long long r = blockIdx.x;
    const int hh = threadIdx.x;
    const int b = (int)(r / SEQ);
    ens[r * 512 + 256 + hh] = cs[b * HID + hh] - tmp[r * HID + hh];
}

// ---------------- launch ----------------
extern "C" void kernel_launch(void* const* d_in, const int* in_sizes, int n_in,
                              void* d_out, int out_size, void* d_ws, size_t ws_size,
                              hipStream_t stream)
{
    const float* x      = (const float*)d_in[0];
    const float* ques_h = (const float*)d_in[1];
    const float* ques_d = (const float*)d_in[2];
    const float* w1ih   = (const float*)d_in[3];
    const float* w1hh   = (const float*)d_in[4];
    const float* b1ih   = (const float*)d_in[5];
    const float* b1hh   = (const float*)d_in[6];
    const float* w2ih   = (const float*)d_in[7];
    const float* w2hh   = (const float*)d_in[8];
    const float* b2ih   = (const float*)d_in[9];
    const float* b2hh   = (const float*)d_in[10];
    const float* fcc_w  = (const float*)d_in[11];
    const float* fcc_b  = (const float*)d_in[12];
    const float* fct_w  = (const float*)d_in[13];
    const float* fct_b  = (const float*)d_in[14];
    const float* fce_w  = (const float*)d_in[15];
    const float* fce_b  = (const float*)d_in[16];

    float* ws = (float*)d_ws;
    // workspace layout (floats) — same 41.4M-float footprint
    float* xh    = ws;                         //  4,096,000
    float* xd    = ws + 4096000LL;             //  4,096,000
    float* xp1   = ws + 8192000LL;             // 12,288,000
    float* xp2   = ws + 20480000LL;            // 12,288,000
    float* outh  = ws + 32768000LL;            //  4,096,000
    float* outd  = ws + 36864000LL;            //  4,096,000
    float* wT1   = ws + 40960000LL;            //    196,608
    float* wT2   = ws + 41156608LL;            //    196,608
    float* cs    = ws + 41353216LL;            //      8,192
    // aliases of dead regions:
    float* quesTh = xp1;                       // dead once xp1 written
    float* quesTd = ws + 9728000LL;
    float* attn   = xp1;                       // xp1 dead after GRU
    float* ens    = xp2;                       // xp2 dead after GRU
    float* tmp    = ws + 28672000LL;           // tail of xp2
    float* outhT  = ws;                        // xh dead after projections
    float* outdT  = ws + 4096000LL;            // xd dead
    // GRU sync buffers in xh region (dead during GRU, overwritten later by outhT)
    float*    gpart = ws;                      // 196,608 (64 grp x 4 kq x 768)
    float*    ghg   = ws + 196608LL;           //  16,384 (64 grp x 256)
    unsigned* gpf   = (unsigned*)(ws + 212992LL);   // 64
    unsigned* ghf   = (unsigned*)(ws + 213056LL);   // 64

    float* out_c = (float*)d_out;              // [16000,3000]
    float* out_t = out_c + 48000000LL;
    float* out_e = out_c + 96000000LL;

    const dim3 blk(256);

    // 0) transpose ques tables to [EMB, 2NQ]
    trans_kernel<<<dim3(8, 188, 1), blk, 0, stream>>>(ques_h, quesTh, X_K, EMB, 0, 0);
    trans_kernel<<<dim3(8, 188, 1), blk, 0, stream>>>(ques_d, quesTd, X_K, EMB, 0, 0);

    // 1) embeddings
    gemm_mfma<false><<<dim3(2, 125, 1), blk, 0, stream>>>(
        x, quesTh, nullptr, xh, ROWS, EMB, X_K, EMB, 0, 0, 0);
    gemm_mfma<false><<<dim3(2, 125, 1), blk, 0, stream>>>(
        x, quesTd, nullptr, xd, ROWS, EMB, X_K, EMB, 0, 0, 0);

    // 2) input projections
    gemm_mfma<true><<<dim3(6, 125, 1), blk, 0, stream>>>(
        xh, w1ih, b1ih, xp1, ROWS, 768, EMB, 768, 0, 0, 0);
    gemm_mfma<true><<<dim3(6, 125, 1), blk, 0, stream>>>(
        xd, w2ih, b2ih, xp2, ROWS, 768, EMB, 768, 0, 0, 0);

    // 3) transpose recurrent weights to [k][768]
    trans_kernel<<<dim3(8, 24, 1), blk, 0, stream>>>(w1hh, wT1, 768, 256, 0, 0);
    trans_kernel<<<dim3(8, 24, 1), blk, 0, stream>>>(w2hh, wT2, 768, 256, 0, 0);

    // 4) dual GRU: init flags/state, then 256-block weights-in-register kernel
    gru_init_kernel<<<64, blk, 0, stream>>>(ghg, gpf, ghf);
    gru_kernel<<<256, blk, 0, stream>>>(xp1, xp2, wT1, wT2, b1hh, b2hh, outh, outd,
                                        gpart, ghg, gpf, ghf);

    // 5) per-branch logits
    gemm_mfma<true><<<dim3(24, 125, 1), blk, 0, stream>>>(
        outh, fcc_w, fcc_b, out_c, ROWS, NQ, HID, NQ, 0, 0, 0);
    gemm_mfma<true><<<dim3(24, 125, 1), blk, 0, stream>>>(
        outd, fct_w, fct_b, out_t, ROWS, NQ, HID, NQ, 0, 0, 0);

    // 6) batched transposes of GRU outputs (overwrite GRU sync bufs — OK, GRU done)
    trans_kernel<<<dim3(8, 16, 32), blk, 0, stream>>>(outh, outhT, SEQ, HID, 128000, 128000);
    trans_kernel<<<dim3(8, 16, 32), blk, 0, stream>>>(outd, outdT, SEQ, HID, 128000, 128000);

    // 7) attention scores
    gemm_mfma<false><<<dim3(4, 4, 32), blk, 0, stream>>>(
        outh, outd, nullptr, attn, SEQ, SEQ, HID, SEQ,
        (long long)SEQ * HID, (long long)SEQ * HID, (long long)SEQ * SEQ);

    // 8) softmax rows
    softmax_kernel<<<ROWS, blk, 0, stream>>>(attn);

    // 9) colsum of outh per batch
    colsum_kernel<<<32, blk, 0, stream>>>(outh, cs);

    // 10) fused_d = attn @ outd; tmp = attn @ outh
    gemm_mfma<false><<<dim3(2, 4, 32), blk, 0, stream>>>(
        attn, outdT, nullptr, ens, SEQ, HID, SEQ, 512,
        (long long)SEQ * SEQ, (long long)HID * SEQ, (long long)SEQ * 512);
    gemm_mfma<false><<<dim3(2, 4, 32), blk, 0, stream>>>(
        attn, outhT, nullptr, tmp, SEQ, HID, SEQ, HID,
        (long long)SEQ * SEQ, (long long)HID * SEQ, (long long)SEQ * HID);

    // 11) ens[:,256:512] = colsum - tmp
    combine_kernel<<<ROWS, blk, 0, stream>>>(tmp, cs, ens);

    // 12) ensemble logits
    gemm_mfma<true><<<dim3(24, 125, 1), blk, 0, stream>>>(
        ens, fce_w, fce_b, out_e, ROWS, NQ, 512, NQ, 0, 0, 0);
}

// Round 10
// 7143.967 us; speedup vs baseline: 1.5837x; 1.5837x over previous
//
#include <hip/hip_runtime.h>
#include <math.h>

// Problem dims
#define BATCH 32
#define SEQ   500
#define NQ    3000
#define EMB   256
#define HID   256
#define ROWS  (BATCH * SEQ)        // 16000
#define X_K   (2 * NQ)             // 6000

typedef short short8 __attribute__((ext_vector_type(8)));
typedef float f32x4  __attribute__((ext_vector_type(4)));

// ---------------- bf16 split helpers ----------------
__device__ __forceinline__ unsigned bf16_rne(float f) {
    unsigned u = __float_as_uint(f);
    return (u + 0x7fffu + ((u >> 16) & 1u)) >> 16;
}
__device__ __forceinline__ unsigned pack_bf16_rn(float a, float b) {
    return bf16_rne(a) | (bf16_rne(b) << 16);   // low16 = a, high16 = b
}
// One 4-element group: {hi01,hi23,lo01,lo23}, pf-swapped for bank spreading.
__device__ __forceinline__ uint4 pack_group(float4 v, int pf) {
    unsigned ux = __float_as_uint(v.x), uy = __float_as_uint(v.y);
    unsigned uz = __float_as_uint(v.z), uw = __float_as_uint(v.w);
    unsigned hx = ux & 0xffff0000u, hy = uy & 0xffff0000u;
    unsigned hz = uz & 0xffff0000u, hw = uw & 0xffff0000u;
    unsigned hi01 = (hx >> 16) | hy;
    unsigned hi23 = (hz >> 16) | hw;
    unsigned lo01 = pack_bf16_rn(v.x - __uint_as_float(hx), v.y - __uint_as_float(hy));
    unsigned lo23 = pack_bf16_rn(v.z - __uint_as_float(hz), v.w - __uint_as_float(hw));
    return pf ? make_uint4(lo01, lo23, hi01, hi23)
              : make_uint4(hi01, hi23, lo01, lo23);
}

// LDS tile layout (128 rows x 32 k, 16 KB): byte(row,cg) = row*128 + ((cg^(row&7))<<4)
__device__ __forceinline__ void stage_f32(unsigned char* lbase, int row, int cg, float4 v) {
    *reinterpret_cast<uint4*>(lbase + row * 128 + (((cg ^ (row & 7))) << 4)) =
        pack_group(v, (row >> 3) & 1);
}
__device__ __forceinline__ void stage_pk(unsigned char* lbase, int row, int cg, uint4 w) {
    *reinterpret_cast<uint4*>(lbase + row * 128 + (((cg ^ (row & 7))) << 4)) = w;
}

__device__ __forceinline__ void read_frag(const unsigned char* lbase, int row, int c,
                                          short8& hi, short8& lo) {
    const int r7 = row & 7;
    const int pf = (row >> 3) & 1;
    const unsigned char* rbase = lbase + row * 128;
    const int s0 = (((c << 1) | 0) ^ r7) << 4;
    const int s1 = (((c << 1) | 1) ^ r7) << 4;
    const int oh = pf << 3;
    const int ol = (pf ^ 1) << 3;
    uint2 h0 = *reinterpret_cast<const uint2*>(rbase + s0 + oh);
    uint2 h1 = *reinterpret_cast<const uint2*>(rbase + s1 + oh);
    uint2 l0 = *reinterpret_cast<const uint2*>(rbase + s0 + ol);
    uint2 l1 = *reinterpret_cast<const uint2*>(rbase + s1 + ol);
    hi = __builtin_bit_cast(short8, make_uint4(h0.x, h0.y, h1.x, h1.y));
    lo = __builtin_bit_cast(short8, make_uint4(l0.x, l0.y, l1.x, l1.y));
}

// ---------------- operand pre-conversion: fp32 -> packed groups ----------------
// rg = groups per row; rpb = rows per batch (pf parity must match TILE-LOCAL row,
// so batched operands use their batch-local row count). In-place safe.
__global__ __launch_bounds__(256)
void convert_kernel(const float* __restrict__ in, uint4* __restrict__ out,
                    long long ngroups, int rg, int rpb)
{
    long long i = (long long)blockIdx.x * 256 + threadIdx.x;
    const long long stride = (long long)gridDim.x * 256;
    for (; i < ngroups; i += stride) {
        float4 v = *reinterpret_cast<const float4*>(in + i * 4);
        const int row = (int)((i / rg) % rpb);
        out[i] = pack_group(v, (row >> 3) & 1);
    }
}

// ---------------- split-bf16 MFMA GEMM ----------------
// C[M,N] = A[M,K] @ B[N,K]^T (+bias). B always packed; A packed unless CONVA.
// sA/sB strides: uint4-group units when packed, element units when CONVA.
template<bool HASBIAS, bool CONVA>
__global__ __launch_bounds__(256, 2)
void gemm_mfma(const void* Av, const uint4* __restrict__ Bpk,
               const float* __restrict__ bias, float* __restrict__ C,
               int M, int N, int K, int ldc,
               long long sA, long long sB, long long sC)
{
    const float* Af  = (const float*)Av;
    const uint4* Apk = (const uint4*)Av;
    if (CONVA) Af  += (long long)blockIdx.z * sA;
    else       Apk += (long long)blockIdx.z * sA;
    Bpk += (long long)blockIdx.z * sB;
    C   += (long long)blockIdx.z * sC;
    const int Kg = K >> 2;

    __shared__ __align__(16) unsigned char lds[32768];
    unsigned char* Al_ = lds;
    unsigned char* Bl_ = lds + 16384;

    const int tid = threadIdx.x;
    const int m0 = blockIdx.y * 128;
    const int n0 = blockIdx.x * 128;

    const int srow = tid >> 3;     // 0..31
    const int scg  = tid & 7;      // 0..7

    const int wid = tid >> 6;
    const int wm  = wid >> 1;
    const int wn  = wid & 1;
    const int lane = tid & 63;
    const int fr  = lane & 15;
    const int fc  = lane >> 4;

    f32x4 acc[4][4];
    #pragma unroll
    for (int i = 0; i < 4; ++i)
        #pragma unroll
        for (int j = 0; j < 4; ++j)
            acc[i][j] = (f32x4){0.f, 0.f, 0.f, 0.f};

    const int ktiles = (K + 31) >> 5;
    for (int kt = 0; kt < ktiles; ++kt) {
        const int gk = (kt << 5) + scg * 4;
        #pragma unroll
        for (int rd = 0; rd < 4; ++rd) {
            const int row = rd * 32 + srow;
            {   // A tile
                const int gm = m0 + row;
                if (CONVA) {
                    float4 v = make_float4(0.f, 0.f, 0.f, 0.f);
                    if (gm < M && gk < K)
                        v = *reinterpret_cast<const float4*>(Af + (long long)gm * K + gk);
                    stage_f32(Al_, row, scg, v);
                } else {
                    uint4 w = make_uint4(0u, 0u, 0u, 0u);
                    if (gm < M && gk < K)
                        w = Apk[(long long)gm * Kg + (gk >> 2)];
                    stage_pk(Al_, row, scg, w);
                }
            }
            {   // B tile (always packed)
                const int gn = n0 + row;
                uint4 w = make_uint4(0u, 0u, 0u, 0u);
                if (gn < N && gk < K)
                    w = Bpk[(long long)gn * Kg + (gk >> 2)];
                stage_pk(Bl_, row, scg, w);
            }
        }
        __syncthreads();

        short8 ah[4], al[4], bh[4], bl[4];
        #pragma unroll
        for (int mi = 0; mi < 4; ++mi)
            read_frag(Al_, wm * 64 + mi * 16 + fr, fc, ah[mi], al[mi]);
        #pragma unroll
        for (int ni = 0; ni < 4; ++ni)
            read_frag(Bl_, wn * 64 + ni * 16 + fr, fc, bh[ni], bl[ni]);

        #pragma unroll
        for (int mi = 0; mi < 4; ++mi) {
            #pragma unroll
            for (int ni = 0; ni < 4; ++ni) {
                acc[mi][ni] = __builtin_amdgcn_mfma_f32_16x16x32_bf16(al[mi], bh[ni], acc[mi][ni], 0, 0, 0);
                acc[mi][ni] = __builtin_amdgcn_mfma_f32_16x16x32_bf16(ah[mi], bl[ni], acc[mi][ni], 0, 0, 0);
                acc[mi][ni] = __builtin_amdgcn_mfma_f32_16x16x32_bf16(ah[mi], bh[ni], acc[mi][ni], 0, 0, 0);
            }
        }
        __syncthreads();
    }

    // epilogue: D mapping col = lane&15, row = (lane>>4)*4 + q  [m89]
    #pragma unroll
    for (int ni = 0; ni < 4; ++ni) {
        const int col = n0 + wn * 64 + ni * 16 + fr;
        if (col >= N) continue;
        const float bv = HASBIAS ? bias[col] : 0.f;
        #pragma unroll
        for (int mi = 0; mi < 4; ++mi) {
            #pragma unroll
            for (int q = 0; q < 4; ++q) {
                const int rw = m0 + wm * 64 + mi * 16 + fc * 4 + q;
                if (rw < M) C[(long long)rw * ldc + col] = acc[mi][ni][q] + bv;
            }
        }
    }
}

// ---------------- generic transpose: in[R,C] -> out[C,R], batched ----------------
__global__ __launch_bounds__(256)
void trans_kernel(const float* __restrict__ in, float* __restrict__ out,
                  int R, int C, long long sIn, long long sOut)
{
    in  += (long long)blockIdx.z * sIn;
    out += (long long)blockIdx.z * sOut;
    __shared__ float t[32][33];
    const int r0 = blockIdx.y * 32, c0 = blockIdx.x * 32;
    const int tx = threadIdx.x & 31, ty = threadIdx.x >> 5;
    #pragma unroll
    for (int i = 0; i < 32; i += 8) {
        const int r = r0 + ty + i, c = c0 + tx;
        t[ty + i][tx] = (r < R && c < C) ? in[(long long)r * C + c] : 0.f;
    }
    __syncthreads();
    #pragma unroll
    for (int i = 0; i < 32; i += 8) {
        const int r = r0 + tx, c = c0 + ty + i;
        if (c < C && r < R) out[(long long)c * R + r] = t[tx][ty + i];
    }
}

// ---------------- GRU (round-5 structure: best measured 3804 us) ----------------
__global__ __launch_bounds__(256)
void gru_kernel(const float* __restrict__ xp1, const float* __restrict__ xp2,
                const float* __restrict__ wT1, const float* __restrict__ wT2,
                const float* __restrict__ bh1, const float* __restrict__ bh2,
                float* __restrict__ out1, float* __restrict__ out2)
{
    const int g = blockIdx.x >> 5;
    const int b = blockIdx.x & 31;
    const float* xp = (g ? xp2 : xp1) + (long long)b * SEQ * 768;
    const float* wT = g ? wT2 : wT1;
    const float* bh = g ? bh2 : bh1;
    float* out      = (g ? out2 : out1) + (long long)b * SEQ * HID;

    __shared__ float h[HID];
    const int j = threadIdx.x;
    h[j] = 0.f;
    const float br = bh[j], bz = bh[HID + j], bn = bh[2 * HID + j];
    __syncthreads();

    for (int t = 0; t < SEQ; ++t) {
        const float* xrow = xp + (long long)t * 768;
        float ar = br, az = bz, an = bn;
        #pragma unroll 8
        for (int k = 0; k < HID; ++k) {
            const float hk = h[k];
            const float* wrow = wT + k * 768;
            ar = fmaf(hk, wrow[j], ar);
            az = fmaf(hk, wrow[HID + j], az);
            an = fmaf(hk, wrow[2 * HID + j], an);
        }
        const float r = 1.f / (1.f + __expf(-(xrow[j] + ar)));
        const float z = 1.f / (1.f + __expf(-(xrow[HID + j] + az)));
        const float n = tanhf(xrow[2 * HID + j] + r * an);
        const float hnew = (1.f - z) * n + z * h[j];
        out[(long long)t * HID + j] = hnew;
        __syncthreads();
        h[j] = hnew;
        __syncthreads();
    }
}

// ---------------- softmax over rows of length 500 (in place) ----------------
__global__ __launch_bounds__(256)
void softmax_kernel(float* __restrict__ s)
{
    float* p = s + (long long)blockIdx.x * SEQ;
    const int tid = threadIdx.x;
    __shared__ float red[256];

    const float v0 = (tid < SEQ) ? p[tid] : -1e30f;
    const float v1 = (tid + 256 < SEQ) ? p[tid + 256] : -1e30f;
    red[tid] = fmaxf(v0, v1);
    __syncthreads();
    for (int o = 128; o > 0; o >>= 1) {
        if (tid < o) red[tid] = fmaxf(red[tid], red[tid + o]);
        __syncthreads();
    }
    const float m = red[0];
    __syncthreads();
    const float e0 = (tid < SEQ) ? __expf(v0 - m) : 0.f;
    const float e1 = (tid + 256 < SEQ) ? __expf(v1 - m) : 0.f;
    red[tid] = e0 + e1;
    __syncthreads();
    for (int o = 128; o > 0; o >>= 1) {
        if (tid < o) red[tid] += red[tid + o];
        __syncthreads();
    }
    const float inv = 1.f / red[0];
    if (tid < SEQ) p[tid] = e0 * inv;
    if (tid + 256 < SEQ) p[tid + 256] = e1 * inv;
}

// ---------------- column sum (fp32 outh, runs BEFORE in-place convert) ----------
__global__ __launch_bounds__(256)
void colsum_kernel(const float* __restrict__ x, float* __restrict__ out)
{
    const int b = blockIdx.x, hh = threadIdx.x;
    const float* p = x + (long long)b * SEQ * HID + hh;
    float s = 0.f;
    for (int t = 0; t < SEQ; ++t) s += p[t * HID];
    out[b * HID + hh] = s;
}

// ---------------- fused_h combine ----------------
__global__ __launch_bounds__(256)
void combine_kernel(const float* __restrict__ tmp, const float* __restrict__ cs,
                    float* __restrict__ ens)
{
    const long long r = blockIdx.x;
    const int hh = threadIdx.x;
    const int b = (int)(r / SEQ);
    ens[r * 512 + 256 + hh] = cs[b * HID + hh] - tmp[r * HID + hh];
}

// ---------------- launch ----------------
extern "C" void kernel_launch(void* const* d_in, const int* in_sizes, int n_in,
                              void* d_out, int out_size, void* d_ws, size_t ws_size,
                              hipStream_t stream)
{
    const float* x      = (const float*)d_in[0];
    const float* ques_h = (const float*)d_in[1];
    const float* ques_d = (const float*)d_in[2];
    const float* w1ih   = (const float*)d_in[3];
    const float* w1hh   = (const float*)d_in[4];
    const float* b1ih   = (const float*)d_in[5];
    const float* b1hh   = (const float*)d_in[6];
    const float* w2ih   = (const float*)d_in[7];
    const float* w2hh   = (const float*)d_in[8];
    const float* b2ih   = (const float*)d_in[9];
    const float* b2hh   = (const float*)d_in[10];
    const float* fcc_w  = (const float*)d_in[11];
    const float* fcc_b  = (const float*)d_in[12];
    const float* fct_w  = (const float*)d_in[13];
    const float* fct_b  = (const float*)d_in[14];
    const float* fce_w  = (const float*)d_in[15];
    const float* fce_b  = (const float*)d_in[16];

    float* ws = (float*)d_ws;
    // fp32 regions
    float* xh    = ws;                         //  4,096,000 (packed in place later)
    float* xd    = ws + 4096000LL;
    float* xp1   = ws + 8192000LL;             // 12,288,000
    float* xp2   = ws + 20480000LL;            // 12,288,000
    float* outh  = ws + 32768000LL;            //  4,096,000 (packed in place later)
    float* outd  = ws + 36864000LL;
    float* wT1   = ws + 40960000LL;            //    196,608
    float* wT2   = ws + 41156608LL;
    float* cs    = ws + 41353216LL;            //      8,192
    // packed weight arena (tail)
    uint4* fcc_c = (uint4*)(ws + 41361408LL);  //   768,000 floats-equiv
    uint4* fct_c = (uint4*)(ws + 42129408LL);
    uint4* fce_c = (uint4*)(ws + 42897408LL);  // 1,536,000
    uint4* w1c   = (uint4*)(ws + 44433408LL);  //   196,608
    uint4* w2c   = (uint4*)(ws + 44630016LL);  //   196,608 -> ends 44,826,624
    // aliases of dead regions
    float* qT1   = ws + 8192000LL;             // 1,536,000 (pre-proj, inside xp1)
    float* qT2   = ws + 9728000LL;
    float* attn  = ws + 8192000LL;             // 8,000,000 (post-GRU, xp1 dead)
    float* ens   = ws + 20480000LL;            // 8,192,000 (xp2 dead post-GRU/attn-pk)
    float* tmp   = ws + 28672000LL;            // 4,096,000
    float* outhT = ws;                         // 4,096,000 (xh_c dead post-proj)
    float* outdT = ws + 4096000LL;
    uint4* oh_apk = (uint4*)(ws + 20480000LL); // 4,096,000 (attn-use copy, dead pre-PV)
    uint4* od_apk = (uint4*)(ws + 24576000LL);

    float* out_c = (float*)d_out;
    float* out_t = out_c + 48000000LL;
    float* out_e = out_c + 96000000LL;

    const dim3 blk(256);
    const dim3 cgrid(1024);

    // 0) ques tables: transpose to [256][6000] fp32, then pack in place (rpb=256)
    trans_kernel<<<dim3(8, 188, 1), blk, 0, stream>>>(ques_h, qT1, X_K, EMB, 0, 0);
    trans_kernel<<<dim3(8, 188, 1), blk, 0, stream>>>(ques_d, qT2, X_K, EMB, 0, 0);
    convert_kernel<<<cgrid, blk, 0, stream>>>(qT1, (uint4*)qT1, 384000, 1500, 256);
    convert_kernel<<<cgrid, blk, 0, stream>>>(qT2, (uint4*)qT2, 384000, 1500, 256);
    // weights packed once
    convert_kernel<<<cgrid, blk, 0, stream>>>(w1ih, w1c, 49152, 64, 768);
    convert_kernel<<<cgrid, blk, 0, stream>>>(w2ih, w2c, 49152, 64, 768);
    convert_kernel<<<cgrid, blk, 0, stream>>>(fcc_w, fcc_c, 192000, 64, 3000);
    convert_kernel<<<cgrid, blk, 0, stream>>>(fct_w, fct_c, 192000, 64, 3000);
    convert_kernel<<<cgrid, blk, 0, stream>>>(fce_w, fce_c, 384000, 128, 3000);

    // 1) embeddings: A = x fp32 (converted in staging), B = packed quesT
    gemm_mfma<false, true><<<dim3(2, 125, 1), blk, 0, stream>>>(
        x, (uint4*)qT1, nullptr, xh, ROWS, EMB, X_K, EMB, 0, 0, 0);
    gemm_mfma<false, true><<<dim3(2, 125, 1), blk, 0, stream>>>(
        x, (uint4*)qT2, nullptr, xd, ROWS, EMB, X_K, EMB, 0, 0, 0);

    // 2) pack xh/xd in place; projections (both operands packed)
    convert_kernel<<<cgrid, blk, 0, stream>>>(xh, (uint4*)xh, 1024000, 64, ROWS);
    convert_kernel<<<cgrid, blk, 0, stream>>>(xd, (uint4*)xd, 1024000, 64, ROWS);
    gemm_mfma<true, false><<<dim3(6, 125, 1), blk, 0, stream>>>(
        (uint4*)xh, w1c, b1ih, xp1, ROWS, 768, EMB, 768, 0, 0, 0);
    gemm_mfma<true, false><<<dim3(6, 125, 1), blk, 0, stream>>>(
        (uint4*)xd, w2c, b2ih, xp2, ROWS, 768, EMB, 768, 0, 0, 0);

    // 3) recurrent weight transpose (fp32, for GRU)
    trans_kernel<<<dim3(8, 24, 1), blk, 0, stream>>>(w1hh, wT1, 768, 256, 0, 0);
    trans_kernel<<<dim3(8, 24, 1), blk, 0, stream>>>(w2hh, wT2, 768, 256, 0, 0);

    // 4) dual GRU (round-5, 64 blocks)
    gru_kernel<<<64, blk, 0, stream>>>(xp1, xp2, wT1, wT2, b1hh, b2hh, outh, outd);

    // 5) post-GRU fp32 consumers first: transposes + colsum
    trans_kernel<<<dim3(8, 16, 32), blk, 0, stream>>>(outh, outhT, SEQ, HID, 128000, 128000);
    trans_kernel<<<dim3(8, 16, 32), blk, 0, stream>>>(outd, outdT, SEQ, HID, 128000, 128000);
    colsum_kernel<<<32, blk, 0, stream>>>(outh, cs);

    // 6) attn-use packed copies (batch-local pf: rpb=500), then in-place packs
    convert_kernel<<<cgrid, blk, 0, stream>>>(outh, oh_apk, 1024000, 64, SEQ);
    convert_kernel<<<cgrid, blk, 0, stream>>>(outd, od_apk, 1024000, 64, SEQ);
    convert_kernel<<<cgrid, blk, 0, stream>>>(outh, (uint4*)outh, 1024000, 64, ROWS);
    convert_kernel<<<cgrid, blk, 0, stream>>>(outd, (uint4*)outd, 1024000, 64, ROWS);
    convert_kernel<<<cgrid, blk, 0, stream>>>(outhT, (uint4*)outhT, 1024000, 125, 256);
    convert_kernel<<<cgrid, blk, 0, stream>>>(outdT, (uint4*)outdT, 1024000, 125, 256);

    // 7) per-branch logits
    gemm_mfma<true, false><<<dim3(24, 125, 1), blk, 0, stream>>>(
        (uint4*)outh, fcc_c, fcc_b, out_c, ROWS, NQ, HID, NQ, 0, 0, 0);
    gemm_mfma<true, false><<<dim3(24, 125, 1), blk, 0, stream>>>(
        (uint4*)outd, fct_c, fct_b, out_t, ROWS, NQ, HID, NQ, 0, 0, 0);

    // 8) attention scores (batched; strides in uint4 groups = 500*64)
    gemm_mfma<false, false><<<dim3(4, 4, 32), blk, 0, stream>>>(
        oh_apk, od_apk, nullptr, attn, SEQ, SEQ, HID, SEQ,
        32000, 32000, (long long)SEQ * SEQ);

    // 9) softmax, then pack attn in place (rpb=500)
    softmax_kernel<<<ROWS, blk, 0, stream>>>(attn);
    convert_kernel<<<cgrid, blk, 0, stream>>>(attn, (uint4*)attn, 2000000, 125, SEQ);

    // 10) PV: A = packed attn (K=500), B = packed out*T
    gemm_mfma<false, false><<<dim3(2, 4, 32), blk, 0, stream>>>(
        (uint4*)attn, (uint4*)outdT, nullptr, ens, SEQ, HID, SEQ, 512,
        62500, 32000, (long long)SEQ * 512);
    gemm_mfma<false, false><<<dim3(2, 4, 32), blk, 0, stream>>>(
        (uint4*)attn, (uint4*)outhT, nullptr, tmp, SEQ, HID, SEQ, HID,
        62500, 32000, (long long)SEQ * HID);

    // 11) combine, pack ens in place, ensemble logits
    combine_kernel<<<ROWS, blk, 0, stream>>>(tmp, cs, ens);
    convert_kernel<<<cgrid, blk, 0, stream>>>(ens, (uint4*)ens, 2048000, 128, ROWS);
    gemm_mfma<true, false><<<dim3(24, 125, 1), blk, 0, stream>>>(
        (uint4*)ens, fce_c, fce_b, out_e, ROWS, NQ, 512, NQ, 0, 0, 0);
}